// Round 11
// baseline (711.295 us; speedup 1.0000x reference)
//
#include <hip/hip_runtime.h>
#include <hip/hip_bf16.h>
#include <hip/hip_cooperative_groups.h>
#include <stdint.h>

namespace cg = cooperative_groups;

#ifndef DRNL
#define DRNL 64
#define HDIM 256
#endif

typedef __attribute__((ext_vector_type(4))) float f32x4;      // MFMA C/D
typedef __attribute__((ext_vector_type(8))) _Float16 f16x8;   // 16B fp16 / MFMA A,B

// ---------------------------------------------------------------------------
// helpers
// ---------------------------------------------------------------------------
// async 16B global -> LDS (lds dest must be wave-uniform-base + lane*16)
__device__ __forceinline__ void async16(void* lds, const void* g) {
    __builtin_amdgcn_global_load_lds(
        (const __attribute__((address_space(1))) void*)g,
        (__attribute__((address_space(3))) void*)(char*)lds, 16, 0, 0);
}

__device__ __forceinline__ int imin(int a, int b) { return a < b ? a : b; }

// ---------------------------------------------------------------------------
// cooperative build kernel: zero + prepX + prepW + bounds + count_indeg +
// scan(rowptr,dis) + CSR fill — one launch, grid.sync between phases.
// ---------------------------------------------------------------------------
__global__ __launch_bounds__(256, 2) void k_build(
    const int* __restrict__ src, const int* __restrict__ dst,
    const int* __restrict__ batch,
    const float* __restrict__ x,
    const float* __restrict__ W0, const float* __restrict__ W1,
    const float* __restrict__ W2,
    int* __restrict__ indeg, int* __restrict__ cursor,
    int* __restrict__ rowptr, int* __restrict__ part,
    int* __restrict__ colA, float* __restrict__ dis,
    int* __restrict__ gstart,
    _Float16* __restrict__ x16,
    _Float16* __restrict__ W0t, _Float16* __restrict__ W1t,
    _Float16* __restrict__ W2t,
    int N, int E, int B, int NC) {
    cg::grid_group grid = cg::this_grid();
    __shared__ int s[256];
    const int tid = threadIdx.x;
    const int gsz = gridDim.x * 256;
    const int gid0 = blockIdx.x * 256 + tid;

    // ---- phase 0: zero indeg+cursor; prepW3; prepX; bounds ----
    for (int i = gid0; i < 2 * N; i += gsz) indeg[i] = 0;  // indeg then cursor (contiguous carve)
    // prepW: (DRNL + 2*HDIM) * 256 elements
    for (int i = gid0; i < (DRNL + 2 * HDIM) * 256; i += gsz) {
        int b = i >> 8, c = i & 255;
        const float* W; _Float16* T; int k, K;
        if (b < DRNL)            { W = W0; T = W0t; k = b;              K = DRNL; }
        else if (b < DRNL + 256) { W = W1; T = W1t; k = b - DRNL;       K = HDIM; }
        else                     { W = W2; T = W2t; k = b - DRNL - 256; K = HDIM; }
        T[(size_t)c * K + k] = (_Float16)W[(size_t)k * 256 + c];
    }
    for (int i = gid0; i < N * DRNL; i += gsz) x16[i] = (_Float16)x[i];
    for (int i = gid0; i <= N; i += gsz) {
        if (i == 0) {
            int b0 = batch[0];
            for (int b = 0; b <= b0; ++b) gstart[b] = 0;
        } else if (i == N) {
            int bl = batch[N - 1];
            for (int b = bl + 1; b <= B; ++b) gstart[b] = N;
        } else {
            int bp = batch[i - 1], bc = batch[i];
            if (bc != bp)
                for (int b = bp + 1; b <= bc; ++b) gstart[b] = i;
        }
    }
    grid.sync();

    // ---- phase 1: count in-degree ----
    for (int e = gid0; e < E; e += gsz) atomicAdd(&indeg[dst[e]], 1);
    grid.sync();

    // ---- phase 2a: per-chunk exclusive scan + dis ----
    for (int c = blockIdx.x; c < NC; c += gridDim.x) {
        int i = c * 256 + tid;
        int v = (i < N) ? indeg[i] : 0;
        if (i < N) dis[i] = rsqrtf((float)(v + 1));
        s[tid] = v;
        __syncthreads();
        for (int off = 1; off < 256; off <<= 1) {
            int t = (tid >= off) ? s[tid - off] : 0;
            __syncthreads();
            s[tid] += t;
            __syncthreads();
        }
        if (i < N) rowptr[i] = s[tid] - v;
        if (tid == 255) part[c] = s[255];
        __syncthreads();
    }
    grid.sync();

    // ---- phase 2b: scan chunk totals (block 0; NC <= 256) ----
    if (blockIdx.x == 0) {
        int v = (tid < NC) ? part[tid] : 0;
        s[tid] = v;
        __syncthreads();
        for (int off = 1; off < 256; off <<= 1) {
            int t = (tid >= off) ? s[tid - off] : 0;
            __syncthreads();
            s[tid] += t;
            __syncthreads();
        }
        if (tid < NC) part[tid] = s[tid] - v;
        if (tid == 0) rowptr[N] = E;
    }
    grid.sync();

    // ---- phase 2c: add chunk offsets ----
    for (int i = gid0; i < N; i += gsz) rowptr[i] += part[i >> 8];
    grid.sync();

    // ---- phase 3: CSR fill (counting sort by dst) ----
    for (int e = gid0; e < E; e += gsz) {
        int d = dst[e];
        int pos = atomicAdd(&cursor[d], 1);
        colA[rowptr[d] + pos] = src[e];
    }
}

// ---------------------------------------------------------------------------
// Aggregation, 64-wide (layer 0): 8 lanes x 16B per edge row -> 8 edges/step
// writes fp16 A
// ---------------------------------------------------------------------------
__global__ __launch_bounds__(256) void k_agg64(const _Float16* __restrict__ x16,
                                               const float* __restrict__ dis,
                                               const int* __restrict__ rowptr,
                                               const int* __restrict__ col,
                                               _Float16* __restrict__ A16, int N) {
    int gw = (blockIdx.x * 256 + threadIdx.x) >> 6;
    int lane = threadIdx.x & 63;
    if (gw >= N) return;
    int g = lane >> 3;      // edge group 0..7
    int fl = lane & 7;      // feature chunk (8 feats = 16B)
    const f16x8* hv = (const f16x8*)x16;   // 8 chunks per row
    float acc[8];
#pragma unroll
    for (int k = 0; k < 8; ++k) acc[k] = 0.f;

    int e0 = rowptr[gw], e1 = rowptr[gw + 1];
    int j = e0 + g;
    for (; j + 8 < e1; j += 16) {
        int s0 = col[j], s1 = col[j + 8];
        float w0 = dis[s0], w1 = dis[s1];
        f16x8 v0 = hv[(size_t)s0 * 8 + fl];
        f16x8 v1 = hv[(size_t)s1 * 8 + fl];
#pragma unroll
        for (int k = 0; k < 8; ++k) acc[k] += w0 * (float)v0[k];
#pragma unroll
        for (int k = 0; k < 8; ++k) acc[k] += w1 * (float)v1[k];
    }
    for (; j < e1; j += 8) {
        int s = col[j];
        float w = dis[s];
        f16x8 v = hv[(size_t)s * 8 + fl];
#pragma unroll
        for (int k = 0; k < 8; ++k) acc[k] += w * (float)v[k];
    }
    // reduce across the 8 edge groups (lanes fl, fl+8, ..., fl+56)
#pragma unroll
    for (int m = 8; m < 64; m <<= 1)
#pragma unroll
        for (int k = 0; k < 8; ++k) acc[k] += __shfl_xor(acc[k], m);

    float dn = dis[gw];
    f16x8 hs = hv[(size_t)gw * 8 + fl];
    f16x8 o;
#pragma unroll
    for (int k = 0; k < 8; ++k)
        o[k] = (_Float16)((acc[k] + dn * (float)hs[k]) * dn);
    if (g == 0) *(f16x8*)(A16 + (size_t)gw * DRNL + fl * 8) = o;
}

// ---------------------------------------------------------------------------
// Aggregation, 256-wide: 32 lanes x 16B per edge, unroll 4, writes fp16 A
// ---------------------------------------------------------------------------
__global__ __launch_bounds__(256) void k_agg256(const _Float16* __restrict__ h16,
                                                const float* __restrict__ dis,
                                                const int* __restrict__ rowptr,
                                                const int* __restrict__ col,
                                                _Float16* __restrict__ A16, int N) {
    int gw = (blockIdx.x * 256 + threadIdx.x) >> 6;
    int lane = threadIdx.x & 63;
    if (gw >= N) return;
    int half = lane >> 5;    // 0/1: edge parity
    int fl = lane & 31;      // feature chunk (8 feats = 16B), 32 chunks = 256
    const f16x8* hv = (const f16x8*)h16;   // 32 chunks per row
    float acc[8];
#pragma unroll
    for (int k = 0; k < 8; ++k) acc[k] = 0.f;

    int e0 = rowptr[gw], e1 = rowptr[gw + 1];
    int j = e0 + half;
    for (; j + 6 < e1; j += 8) {
        int s0 = col[j], s1 = col[j + 2], s2 = col[j + 4], s3 = col[j + 6];
        float w0 = dis[s0], w1 = dis[s1], w2 = dis[s2], w3 = dis[s3];
        f16x8 v0 = hv[(size_t)s0 * 32 + fl];
        f16x8 v1 = hv[(size_t)s1 * 32 + fl];
        f16x8 v2 = hv[(size_t)s2 * 32 + fl];
        f16x8 v3 = hv[(size_t)s3 * 32 + fl];
#pragma unroll
        for (int k = 0; k < 8; ++k) acc[k] += w0 * (float)v0[k];
#pragma unroll
        for (int k = 0; k < 8; ++k) acc[k] += w1 * (float)v1[k];
#pragma unroll
        for (int k = 0; k < 8; ++k) acc[k] += w2 * (float)v2[k];
#pragma unroll
        for (int k = 0; k < 8; ++k) acc[k] += w3 * (float)v3[k];
    }
    for (; j < e1; j += 2) {
        int s = col[j];
        float w = dis[s];
        f16x8 v = hv[(size_t)s * 32 + fl];
#pragma unroll
        for (int k = 0; k < 8; ++k) acc[k] += w * (float)v[k];
    }
    // combine the two halves
#pragma unroll
    for (int k = 0; k < 8; ++k) acc[k] += __shfl_xor(acc[k], 32);

    float dn = dis[gw];
    f16x8 hs = hv[(size_t)gw * 32 + fl];
    f16x8 o;
#pragma unroll
    for (int k = 0; k < 8; ++k)
        o[k] = (_Float16)((acc[k] + dn * (float)hs[k]) * dn);
    if (half == 0) *(f16x8*)(A16 + (size_t)gw * HDIM + fl * 8) = o;
}

// ---------------------------------------------------------------------------
// fp16 MFMA GEMM: out = A@W + bias.  A [n][K] fp16; W [256][K] fp16.
// Block 128 rows x 256 cols, 4 waves. 1 MFMA/16x16 tile. LDS 24 KB.
// ---------------------------------------------------------------------------
template <int K, int OUT_RELU>
__global__ __launch_bounds__(256, 2) void k_mgemm(const _Float16* __restrict__ A,
                                                  const _Float16* __restrict__ W,
                                                  const float* __restrict__ bias,
                                                  _Float16* __restrict__ outh, int n) {
    __shared__ _Float16 sA[128 * 32];   // 8 KB
    __shared__ _Float16 sW[256 * 32];   // 16 KB

    const int tid = threadIdx.x;
    const int lane = tid & 63;
    const int w = tid >> 6;
    const int c15 = lane & 15;
    const int q = lane >> 4;
    const int row0 = blockIdx.x * 128;

    f32x4 acc[8][4];
#pragma unroll
    for (int i = 0; i < 8; ++i)
#pragma unroll
        for (int j = 0; j < 4; ++j) acc[i][j] = (f32x4)0.f;

    for (int kt = 0; kt < K; kt += 32) {
        // ---- stage A: 512 16B-units ----
#pragma unroll
        for (int i = 0; i < 2; ++i) {
            int u = tid + (i << 8);
            int row = u >> 2;
            int qq = (u & 3) ^ ((row >> 1) & 3);
            size_t goff = (size_t)imin(row0 + row, n - 1) * K + kt + qq * 8;
            async16(sA + u * 8, A + goff);
        }
        // ---- stage W: 1024 16B-units ----
#pragma unroll
        for (int i = 0; i < 4; ++i) {
            int u = tid + (i << 8);
            int c = u >> 2;
            int qq = (u & 3) ^ ((c >> 1) & 3);
            size_t goff = (size_t)c * K + kt + qq * 8;
            async16(sW + u * 8, W + goff);
        }
        __syncthreads();

        f16x8 wf[4];
#pragma unroll
        for (int ct = 0; ct < 4; ++ct) {
            int c = (w << 6) + (ct << 4) + c15;
            int u = (c << 2) + (q ^ ((c >> 1) & 3));
            wf[ct] = *(const f16x8*)(sW + u * 8);
        }
#pragma unroll
        for (int rt = 0; rt < 8; ++rt) {
            int r = (rt << 4) + c15;
            int u = (r << 2) + (q ^ ((r >> 1) & 3));
            f16x8 a = *(const f16x8*)(sA + u * 8);
#pragma unroll
            for (int ct = 0; ct < 4; ++ct)
                acc[rt][ct] = __builtin_amdgcn_mfma_f32_16x16x32_f16(a, wf[ct], acc[rt][ct], 0, 0, 0);
        }
        __syncthreads();
    }

    // ---- epilogue: C/D layout col=lane&15, row=(lane>>4)*4+reg ----
#pragma unroll
    for (int ct = 0; ct < 4; ++ct) {
        int c = (w << 6) + (ct << 4) + c15;
        float bv = bias[c];
#pragma unroll
        for (int rt = 0; rt < 8; ++rt) {
#pragma unroll
            for (int r = 0; r < 4; ++r) {
                int row = row0 + (rt << 4) + (q << 2) + r;
                if (row < n) {
                    float v = acc[rt][ct][r] + bv;
                    if (OUT_RELU) v = fmaxf(v, 0.f);
                    outh[(size_t)row * HDIM + c] = (_Float16)v;
                }
            }
        }
    }
}

// ---------------------------------------------------------------------------
// fused head: mean-pool + concat + MLP -> out[b]. one block per graph.
// ---------------------------------------------------------------------------
__global__ __launch_bounds__(256) void k_head(const _Float16* __restrict__ h,
                                              const int* __restrict__ gstart,
                                              const int* __restrict__ u,
                                              const int* __restrict__ v,
                                              const float* __restrict__ Wm1,
                                              const float* __restrict__ bm1,
                                              const float* __restrict__ Wm2,
                                              const float* __restrict__ bm2,
                                              float* __restrict__ out) {
    int b = blockIdx.x;
    int t = threadIdx.x;
    __shared__ float z[3 * HDIM];
    __shared__ float red[4];
    // mean pool, 4 rows in flight
    int s = gstart[b], e = gstart[b + 1];
    float pa = 0.f;
    int i = s;
    for (; i + 3 < e; i += 4) {
        float a0 = (float)h[(size_t)i * HDIM + t];
        float a1 = (float)h[(size_t)(i + 1) * HDIM + t];
        float a2 = (float)h[(size_t)(i + 2) * HDIM + t];
        float a3 = (float)h[(size_t)(i + 3) * HDIM + t];
        pa += (a0 + a1) + (a2 + a3);
    }
    for (; i < e; ++i) pa += (float)h[(size_t)i * HDIM + t];
    z[t]            = pa / fmaxf((float)(e - s), 1.f);
    z[HDIM + t]     = (float)h[(size_t)u[b] * HDIM + t];
    z[2 * HDIM + t] = (float)h[(size_t)v[b] * HDIM + t];
    __syncthreads();
    // MLP, 8 independent chains
    float acc[8];
#pragma unroll
    for (int k = 0; k < 8; ++k) acc[k] = 0.f;
    for (int k = 0; k < 3 * HDIM; k += 8) {
#pragma unroll
        for (int jj = 0; jj < 8; ++jj)
            acc[jj] = fmaf(z[k + jj], Wm1[(size_t)(k + jj) * HDIM + t], acc[jj]);
    }
    float sum = (((acc[0] + acc[1]) + (acc[2] + acc[3])) +
                 ((acc[4] + acc[5]) + (acc[6] + acc[7]))) + bm1[t];
    float hid = fmaxf(sum, 0.f);
    float p = hid * Wm2[t];
    for (int off = 32; off; off >>= 1) p += __shfl_down(p, off);
    if ((t & 63) == 0) red[t >> 6] = p;
    __syncthreads();
    if (t == 0) out[b] = red[0] + red[1] + red[2] + red[3] + bm2[0];
}

// ---------------------------------------------------------------------------
extern "C" void kernel_launch(void* const* d_in, const int* in_sizes, int n_in,
                              void* d_out, int out_size, void* d_ws, size_t ws_size,
                              hipStream_t stream) {
    const float* x    = (const float*)d_in[0];
    const int*   ei   = (const int*)d_in[1];
    const int*   batc = (const int*)d_in[2];
    const int*   uidx = (const int*)d_in[3];
    const int*   vidx = (const int*)d_in[4];
    const float* W0   = (const float*)d_in[5];
    const float* b0   = (const float*)d_in[6];
    const float* W1   = (const float*)d_in[7];
    const float* b1   = (const float*)d_in[8];
    const float* W2   = (const float*)d_in[9];
    const float* b2   = (const float*)d_in[10];
    const float* Wm1  = (const float*)d_in[11];
    const float* bm1  = (const float*)d_in[12];
    const float* Wm2  = (const float*)d_in[13];
    const float* bm2  = (const float*)d_in[14];
    float* out = (float*)d_out;

    const int N = in_sizes[0] / DRNL;
    const int E = in_sizes[1] / 2;
    const int B = in_sizes[3];
    const int* src = ei;
    const int* dst = ei + E;
    const int NC = (N + 255) / 256;

    char* w = (char*)d_ws;
    size_t off = 0;
    auto carve = [&](size_t bytes) {
        void* p = w + off;
        off = (off + bytes + 255) & ~(size_t)255;
        return p;
    };
    // indeg and cursor carved as ONE block (zeroed together in k_build phase 0)
    int*       indeg  = (int*)carve((size_t)N * 8);
    int*       cursor = indeg + N;
    int*       rowptr = (int*)carve((size_t)(N + 1) * 4);
    int*       part   = (int*)carve(256 * 4);
    int*       colA   = (int*)carve((size_t)E * 4);
    float*     dis    = (float*)carve((size_t)N * 4);
    int*       gstart = (int*)carve((size_t)(B + 1) * 4);
    _Float16*  A16    = (_Float16*)carve((size_t)N * HDIM * 2);
    _Float16*  h16    = (_Float16*)carve((size_t)N * HDIM * 2);
    _Float16*  x16    = (_Float16*)carve((size_t)N * DRNL * 2);
    _Float16*  W0t    = (_Float16*)carve((size_t)DRNL * HDIM * 2);
    _Float16*  W1t    = (_Float16*)carve((size_t)HDIM * HDIM * 2);
    _Float16*  W2t    = (_Float16*)carve((size_t)HDIM * HDIM * 2);
    (void)ws_size;

    // ---- one cooperative launch for the whole preprocessing chain ----
    {
        int Ni = N, Ei = E, Bi = B, NCi = NC;
        void* args[] = {
            (void*)&src, (void*)&dst, (void*)&batc,
            (void*)&x, (void*)&W0, (void*)&W1, (void*)&W2,
            (void*)&indeg, (void*)&cursor, (void*)&rowptr, (void*)&part,
            (void*)&colA, (void*)&dis, (void*)&gstart,
            (void*)&x16, (void*)&W0t, (void*)&W1t, (void*)&W2t,
            (void*)&Ni, (void*)&Ei, (void*)&Bi, (void*)&NCi,
        };
        hipLaunchCooperativeKernel((void*)k_build, dim3(512), dim3(256),
                                   args, 0, stream);
    }

    int aggb = (N + 3) / 4;
    int gemmb = (N + 127) / 128;

    // layer 0: agg(x16) -> GEMM -> h16 (relu)
    k_agg64<<<aggb, 256, 0, stream>>>(x16, dis, rowptr, colA, A16, N);
    k_mgemm<DRNL, 1><<<gemmb, 256, 0, stream>>>(A16, W0t, b0, h16, N);
    // layer 1: agg(h16) -> GEMM -> h16 (relu)
    k_agg256<<<aggb, 256, 0, stream>>>(h16, dis, rowptr, colA, A16, N);
    k_mgemm<HDIM, 1><<<gemmb, 256, 0, stream>>>(A16, W1t, b1, h16, N);
    // layer 2: agg(h16) -> GEMM -> h16 (no relu)
    k_agg256<<<aggb, 256, 0, stream>>>(h16, dis, rowptr, colA, A16, N);
    k_mgemm<HDIM, 0><<<gemmb, 256, 0, stream>>>(A16, W2t, b2, h16, N);

    // fused mean-pool + MLP head
    k_head<<<B, 256, 0, stream>>>(h16, gstart, uidx, vidx, Wm1, bm1, Wm2, bm2, out);
}

// Round 12
// 414.029 us; speedup vs baseline: 1.7180x; 1.7180x over previous
//
#include <hip/hip_runtime.h>
#include <hip/hip_bf16.h>
#include <stdint.h>

#ifndef DRNL
#define DRNL 64
#define HDIM 256
#endif

typedef __attribute__((ext_vector_type(4))) float f32x4;      // MFMA C/D
typedef __attribute__((ext_vector_type(8))) _Float16 f16x8;   // 16B fp16 / MFMA A,B

// ---------------------------------------------------------------------------
// helpers
// ---------------------------------------------------------------------------
// async 16B global -> LDS (lds dest must be wave-uniform-base + lane*16)
__device__ __forceinline__ void async16(void* lds, const void* g) {
    __builtin_amdgcn_global_load_lds(
        (const __attribute__((address_space(1))) void*)g,
        (__attribute__((address_space(3))) void*)(char*)lds, 16, 0, 0);
}

__device__ __forceinline__ int imin(int a, int b) { return a < b ? a : b; }

// ---------------------------------------------------------------------------
// k_misc: all order-independent prep in ONE launch (no grid.sync needed):
// zero(indeg+cursor), prepW3 (f32 -> transposed fp16), prepX, bounds.
// ---------------------------------------------------------------------------
__global__ __launch_bounds__(256) void k_misc(
    const int* __restrict__ batch,
    const float* __restrict__ x,
    const float* __restrict__ W0, const float* __restrict__ W1,
    const float* __restrict__ W2,
    int* __restrict__ indeg,          // zeroes 2N ints (indeg + cursor)
    int* __restrict__ gstart,
    _Float16* __restrict__ x16,
    _Float16* __restrict__ W0t, _Float16* __restrict__ W1t,
    _Float16* __restrict__ W2t,
    int N, int B) {
    const int gsz = gridDim.x * 256;
    const int gid0 = blockIdx.x * 256 + threadIdx.x;

    for (int i = gid0; i < 2 * N; i += gsz) indeg[i] = 0;

    for (int i = gid0; i < (DRNL + 2 * HDIM) * 256; i += gsz) {
        int b = i >> 8, c = i & 255;
        const float* W; _Float16* T; int k, K;
        if (b < DRNL)            { W = W0; T = W0t; k = b;              K = DRNL; }
        else if (b < DRNL + 256) { W = W1; T = W1t; k = b - DRNL;       K = HDIM; }
        else                     { W = W2; T = W2t; k = b - DRNL - 256; K = HDIM; }
        T[(size_t)c * K + k] = (_Float16)W[(size_t)k * 256 + c];
    }

    for (int i = gid0; i < N * DRNL; i += gsz) x16[i] = (_Float16)x[i];

    for (int i = gid0; i <= N; i += gsz) {
        if (i == 0) {
            int b0 = batch[0];
            for (int b = 0; b <= b0; ++b) gstart[b] = 0;
        } else if (i == N) {
            int bl = batch[N - 1];
            for (int b = bl + 1; b <= B; ++b) gstart[b] = N;
        } else {
            int bp = batch[i - 1], bc = batch[i];
            if (bc != bp)
                for (int b = bp + 1; b <= bc; ++b) gstart[b] = i;
        }
    }
}

// ---------------------------------------------------------------------------
// degree count (in-degree from dst)
// ---------------------------------------------------------------------------
__global__ __launch_bounds__(256) void k_count_indeg(const int* __restrict__ dst,
                                                     int* __restrict__ indeg, int E) {
    int e = blockIdx.x * 256 + threadIdx.x;
    if (e < E) atomicAdd(&indeg[dst[e]], 1);
}

// ---------------------------------------------------------------------------
// exclusive scan of indeg -> rowptr (also emits dis = rsqrt(indeg+1))
// ---------------------------------------------------------------------------
__global__ __launch_bounds__(256) void k_scan1(const int* __restrict__ in,
                                               int* __restrict__ out,
                                               int* __restrict__ partial,
                                               float* __restrict__ dis, int n) {
    __shared__ int s[256];
    int tid = threadIdx.x;
    int i = blockIdx.x * 256 + tid;
    int v = (i < n) ? in[i] : 0;
    if (i < n) dis[i] = rsqrtf((float)(v + 1));
    s[tid] = v;
    __syncthreads();
    for (int off = 1; off < 256; off <<= 1) {
        int t = (tid >= off) ? s[tid - off] : 0;
        __syncthreads();
        s[tid] += t;
        __syncthreads();
    }
    if (i < n) out[i] = s[tid] - v;
    if (tid == 255) partial[blockIdx.x] = s[255];
}

__global__ __launch_bounds__(256) void k_scan2(int* __restrict__ partial, int nb,
                                               int* __restrict__ rowptr, int n, int total) {
    __shared__ int s[256];
    int tid = threadIdx.x;
    int v = (tid < nb) ? partial[tid] : 0;
    s[tid] = v;
    __syncthreads();
    for (int off = 1; off < 256; off <<= 1) {
        int t = (tid >= off) ? s[tid - off] : 0;
        __syncthreads();
        s[tid] += t;
        __syncthreads();
    }
    if (tid < nb) partial[tid] = s[tid] - v;
    if (tid == 0) rowptr[n] = total;
}

__global__ __launch_bounds__(256) void k_scan3(int* __restrict__ rowptr,
                                               const int* __restrict__ partial, int n) {
    int i = blockIdx.x * 256 + threadIdx.x;
    if (i < n) rowptr[i] += partial[blockIdx.x];
}

// ---------------------------------------------------------------------------
// CSR fill (counting sort by dst)
// ---------------------------------------------------------------------------
__global__ __launch_bounds__(256) void k_fill(const int* __restrict__ src,
                                              const int* __restrict__ dst,
                                              const int* __restrict__ rowptr,
                                              int* __restrict__ cursor,
                                              int* __restrict__ col, int E) {
    int e = blockIdx.x * 256 + threadIdx.x;
    if (e < E) {
        int d = dst[e];
        int pos = atomicAdd(&cursor[d], 1);
        col[rowptr[d] + pos] = src[e];
    }
}

// ---------------------------------------------------------------------------
// Aggregation, 64-wide (layer 0): 8 lanes x 16B per edge row -> 8 edges/step
// writes fp16 A
// ---------------------------------------------------------------------------
__global__ __launch_bounds__(256) void k_agg64(const _Float16* __restrict__ x16,
                                               const float* __restrict__ dis,
                                               const int* __restrict__ rowptr,
                                               const int* __restrict__ col,
                                               _Float16* __restrict__ A16, int N) {
    int gw = (blockIdx.x * 256 + threadIdx.x) >> 6;
    int lane = threadIdx.x & 63;
    if (gw >= N) return;
    int g = lane >> 3;      // edge group 0..7
    int fl = lane & 7;      // feature chunk (8 feats = 16B)
    const f16x8* hv = (const f16x8*)x16;   // 8 chunks per row
    float acc[8];
#pragma unroll
    for (int k = 0; k < 8; ++k) acc[k] = 0.f;

    int e0 = rowptr[gw], e1 = rowptr[gw + 1];
    int j = e0 + g;
    for (; j + 8 < e1; j += 16) {
        int s0 = col[j], s1 = col[j + 8];
        float w0 = dis[s0], w1 = dis[s1];
        f16x8 v0 = hv[(size_t)s0 * 8 + fl];
        f16x8 v1 = hv[(size_t)s1 * 8 + fl];
#pragma unroll
        for (int k = 0; k < 8; ++k) acc[k] += w0 * (float)v0[k];
#pragma unroll
        for (int k = 0; k < 8; ++k) acc[k] += w1 * (float)v1[k];
    }
    for (; j < e1; j += 8) {
        int s = col[j];
        float w = dis[s];
        f16x8 v = hv[(size_t)s * 8 + fl];
#pragma unroll
        for (int k = 0; k < 8; ++k) acc[k] += w * (float)v[k];
    }
    // reduce across the 8 edge groups (lanes fl, fl+8, ..., fl+56)
#pragma unroll
    for (int m = 8; m < 64; m <<= 1)
#pragma unroll
        for (int k = 0; k < 8; ++k) acc[k] += __shfl_xor(acc[k], m);

    float dn = dis[gw];
    f16x8 hs = hv[(size_t)gw * 8 + fl];
    f16x8 o;
#pragma unroll
    for (int k = 0; k < 8; ++k)
        o[k] = (_Float16)((acc[k] + dn * (float)hs[k]) * dn);
    if (g == 0) *(f16x8*)(A16 + (size_t)gw * DRNL + fl * 8) = o;
}

// ---------------------------------------------------------------------------
// Aggregation, 256-wide: 32 lanes x 16B per edge, unroll 4, writes fp16 A
// ---------------------------------------------------------------------------
__global__ __launch_bounds__(256) void k_agg256(const _Float16* __restrict__ h16,
                                                const float* __restrict__ dis,
                                                const int* __restrict__ rowptr,
                                                const int* __restrict__ col,
                                                _Float16* __restrict__ A16, int N) {
    int gw = (blockIdx.x * 256 + threadIdx.x) >> 6;
    int lane = threadIdx.x & 63;
    if (gw >= N) return;
    int half = lane >> 5;    // 0/1: edge parity
    int fl = lane & 31;      // feature chunk (8 feats = 16B), 32 chunks = 256
    const f16x8* hv = (const f16x8*)h16;   // 32 chunks per row
    float acc[8];
#pragma unroll
    for (int k = 0; k < 8; ++k) acc[k] = 0.f;

    int e0 = rowptr[gw], e1 = rowptr[gw + 1];
    int j = e0 + half;
    for (; j + 6 < e1; j += 8) {
        int s0 = col[j], s1 = col[j + 2], s2 = col[j + 4], s3 = col[j + 6];
        float w0 = dis[s0], w1 = dis[s1], w2 = dis[s2], w3 = dis[s3];
        f16x8 v0 = hv[(size_t)s0 * 32 + fl];
        f16x8 v1 = hv[(size_t)s1 * 32 + fl];
        f16x8 v2 = hv[(size_t)s2 * 32 + fl];
        f16x8 v3 = hv[(size_t)s3 * 32 + fl];
#pragma unroll
        for (int k = 0; k < 8; ++k) acc[k] += w0 * (float)v0[k];
#pragma unroll
        for (int k = 0; k < 8; ++k) acc[k] += w1 * (float)v1[k];
#pragma unroll
        for (int k = 0; k < 8; ++k) acc[k] += w2 * (float)v2[k];
#pragma unroll
        for (int k = 0; k < 8; ++k) acc[k] += w3 * (float)v3[k];
    }
    for (; j < e1; j += 2) {
        int s = col[j];
        float w = dis[s];
        f16x8 v = hv[(size_t)s * 32 + fl];
#pragma unroll
        for (int k = 0; k < 8; ++k) acc[k] += w * (float)v[k];
    }
    // combine the two halves
#pragma unroll
    for (int k = 0; k < 8; ++k) acc[k] += __shfl_xor(acc[k], 32);

    float dn = dis[gw];
    f16x8 hs = hv[(size_t)gw * 32 + fl];
    f16x8 o;
#pragma unroll
    for (int k = 0; k < 8; ++k)
        o[k] = (_Float16)((acc[k] + dn * (float)hs[k]) * dn);
    if (half == 0) *(f16x8*)(A16 + (size_t)gw * HDIM + fl * 8) = o;
}

// ---------------------------------------------------------------------------
// fp16 MFMA GEMM: out = A@W + bias.  A [n][K] fp16; W [256][K] fp16.
// Block 128 rows x 256 cols, 4 waves. 1 MFMA/16x16 tile. LDS 24 KB.
// ---------------------------------------------------------------------------
template <int K, int OUT_RELU>
__global__ __launch_bounds__(256, 2) void k_mgemm(const _Float16* __restrict__ A,
                                                  const _Float16* __restrict__ W,
                                                  const float* __restrict__ bias,
                                                  _Float16* __restrict__ outh, int n) {
    __shared__ _Float16 sA[128 * 32];   // 8 KB
    __shared__ _Float16 sW[256 * 32];   // 16 KB

    const int tid = threadIdx.x;
    const int lane = tid & 63;
    const int w = tid >> 6;
    const int c15 = lane & 15;
    const int q = lane >> 4;
    const int row0 = blockIdx.x * 128;

    f32x4 acc[8][4];
#pragma unroll
    for (int i = 0; i < 8; ++i)
#pragma unroll
        for (int j = 0; j < 4; ++j) acc[i][j] = (f32x4)0.f;

    for (int kt = 0; kt < K; kt += 32) {
        // ---- stage A: 512 16B-units ----
#pragma unroll
        for (int i = 0; i < 2; ++i) {
            int u = tid + (i << 8);
            int row = u >> 2;
            int qq = (u & 3) ^ ((row >> 1) & 3);
            size_t goff = (size_t)imin(row0 + row, n - 1) * K + kt + qq * 8;
            async16(sA + u * 8, A + goff);
        }
        // ---- stage W: 1024 16B-units ----
#pragma unroll
        for (int i = 0; i < 4; ++i) {
            int u = tid + (i << 8);
            int c = u >> 2;
            int qq = (u & 3) ^ ((c >> 1) & 3);
            size_t goff = (size_t)c * K + kt + qq * 8;
            async16(sW + u * 8, W + goff);
        }
        __syncthreads();

        f16x8 wf[4];
#pragma unroll
        for (int ct = 0; ct < 4; ++ct) {
            int c = (w << 6) + (ct << 4) + c15;
            int u = (c << 2) + (q ^ ((c >> 1) & 3));
            wf[ct] = *(const f16x8*)(sW + u * 8);
        }
#pragma unroll
        for (int rt = 0; rt < 8; ++rt) {
            int r = (rt << 4) + c15;
            int u = (r << 2) + (q ^ ((r >> 1) & 3));
            f16x8 a = *(const f16x8*)(sA + u * 8);
#pragma unroll
            for (int ct = 0; ct < 4; ++ct)
                acc[rt][ct] = __builtin_amdgcn_mfma_f32_16x16x32_f16(a, wf[ct], acc[rt][ct], 0, 0, 0);
        }
        __syncthreads();
    }

    // ---- epilogue: C/D layout col=lane&15, row=(lane>>4)*4+reg ----
#pragma unroll
    for (int ct = 0; ct < 4; ++ct) {
        int c = (w << 6) + (ct << 4) + c15;
        float bv = bias[c];
#pragma unroll
        for (int rt = 0; rt < 8; ++rt) {
#pragma unroll
            for (int r = 0; r < 4; ++r) {
                int row = row0 + (rt << 4) + (q << 2) + r;
                if (row < n) {
                    float v = acc[rt][ct][r] + bv;
                    if (OUT_RELU) v = fmaxf(v, 0.f);
                    outh[(size_t)row * HDIM + c] = (_Float16)v;
                }
            }
        }
    }
}

// ---------------------------------------------------------------------------
// fused head: mean-pool + concat + MLP -> out[b]. one block per graph.
// ---------------------------------------------------------------------------
__global__ __launch_bounds__(256) void k_head(const _Float16* __restrict__ h,
                                              const int* __restrict__ gstart,
                                              const int* __restrict__ u,
                                              const int* __restrict__ v,
                                              const float* __restrict__ Wm1,
                                              const float* __restrict__ bm1,
                                              const float* __restrict__ Wm2,
                                              const float* __restrict__ bm2,
                                              float* __restrict__ out) {
    int b = blockIdx.x;
    int t = threadIdx.x;
    __shared__ float z[3 * HDIM];
    __shared__ float red[4];
    // mean pool, 4 rows in flight
    int s = gstart[b], e = gstart[b + 1];
    float pa = 0.f;
    int i = s;
    for (; i + 3 < e; i += 4) {
        float a0 = (float)h[(size_t)i * HDIM + t];
        float a1 = (float)h[(size_t)(i + 1) * HDIM + t];
        float a2 = (float)h[(size_t)(i + 2) * HDIM + t];
        float a3 = (float)h[(size_t)(i + 3) * HDIM + t];
        pa += (a0 + a1) + (a2 + a3);
    }
    for (; i < e; ++i) pa += (float)h[(size_t)i * HDIM + t];
    z[t]            = pa / fmaxf((float)(e - s), 1.f);
    z[HDIM + t]     = (float)h[(size_t)u[b] * HDIM + t];
    z[2 * HDIM + t] = (float)h[(size_t)v[b] * HDIM + t];
    __syncthreads();
    // MLP, 8 independent chains
    float acc[8];
#pragma unroll
    for (int k = 0; k < 8; ++k) acc[k] = 0.f;
    for (int k = 0; k < 3 * HDIM; k += 8) {
#pragma unroll
        for (int jj = 0; jj < 8; ++jj)
            acc[jj] = fmaf(z[k + jj], Wm1[(size_t)(k + jj) * HDIM + t], acc[jj]);
    }
    float sum = (((acc[0] + acc[1]) + (acc[2] + acc[3])) +
                 ((acc[4] + acc[5]) + (acc[6] + acc[7]))) + bm1[t];
    float hid = fmaxf(sum, 0.f);
    float p = hid * Wm2[t];
    for (int off = 32; off; off >>= 1) p += __shfl_down(p, off);
    if ((t & 63) == 0) red[t >> 6] = p;
    __syncthreads();
    if (t == 0) out[b] = red[0] + red[1] + red[2] + red[3] + bm2[0];
}

// ---------------------------------------------------------------------------
extern "C" void kernel_launch(void* const* d_in, const int* in_sizes, int n_in,
                              void* d_out, int out_size, void* d_ws, size_t ws_size,
                              hipStream_t stream) {
    const float* x    = (const float*)d_in[0];
    const int*   ei   = (const int*)d_in[1];
    const int*   batc = (const int*)d_in[2];
    const int*   uidx = (const int*)d_in[3];
    const int*   vidx = (const int*)d_in[4];
    const float* W0   = (const float*)d_in[5];
    const float* b0   = (const float*)d_in[6];
    const float* W1   = (const float*)d_in[7];
    const float* b1   = (const float*)d_in[8];
    const float* W2   = (const float*)d_in[9];
    const float* b2   = (const float*)d_in[10];
    const float* Wm1  = (const float*)d_in[11];
    const float* bm1  = (const float*)d_in[12];
    const float* Wm2  = (const float*)d_in[13];
    const float* bm2  = (const float*)d_in[14];
    float* out = (float*)d_out;

    const int N = in_sizes[0] / DRNL;
    const int E = in_sizes[1] / 2;
    const int B = in_sizes[3];
    const int* src = ei;
    const int* dst = ei + E;

    char* w = (char*)d_ws;
    size_t off = 0;
    auto carve = [&](size_t bytes) {
        void* p = w + off;
        off = (off + bytes + 255) & ~(size_t)255;
        return p;
    };
    // indeg and cursor carved as ONE block (zeroed together in k_misc)
    int*       indeg  = (int*)carve((size_t)N * 8);
    int*       cursor = indeg + N;
    int*       rowptr = (int*)carve((size_t)(N + 1) * 4);
    int*       part   = (int*)carve(256 * 4);
    int*       colA   = (int*)carve((size_t)E * 4);
    float*     dis    = (float*)carve((size_t)N * 4);
    int*       gstart = (int*)carve((size_t)(B + 1) * 4);
    _Float16*  A16    = (_Float16*)carve((size_t)N * HDIM * 2);
    _Float16*  h16    = (_Float16*)carve((size_t)N * HDIM * 2);
    _Float16*  x16    = (_Float16*)carve((size_t)N * DRNL * 2);
    _Float16*  W0t    = (_Float16*)carve((size_t)DRNL * HDIM * 2);
    _Float16*  W1t    = (_Float16*)carve((size_t)HDIM * HDIM * 2);
    _Float16*  W2t    = (_Float16*)carve((size_t)HDIM * HDIM * 2);
    (void)ws_size;

    int eb = (E + 255) / 256;
    int nb = (N + 255) / 256;

    // one launch for all order-independent prep (zero, prepW, prepX, bounds)
    k_misc<<<1024, 256, 0, stream>>>(batc, x, W0, W1, W2, indeg, gstart,
                                     x16, W0t, W1t, W2t, N, B);
    // CSR chain (true dependencies)
    k_count_indeg<<<eb, 256, 0, stream>>>(dst, indeg, E);
    k_scan1<<<nb, 256, 0, stream>>>(indeg, rowptr, part, dis, N);
    k_scan2<<<1, 256, 0, stream>>>(part, nb, rowptr, N, E);
    k_scan3<<<nb, 256, 0, stream>>>(rowptr, part, N);
    k_fill<<<eb, 256, 0, stream>>>(src, dst, rowptr, cursor, colA, E);

    int aggb = (N + 3) / 4;
    int gemmb = (N + 127) / 128;

    // layer 0: agg(x16) -> GEMM -> h16 (relu)
    k_agg64<<<aggb, 256, 0, stream>>>(x16, dis, rowptr, colA, A16, N);
    k_mgemm<DRNL, 1><<<gemmb, 256, 0, stream>>>(A16, W0t, b0, h16, N);
    // layer 1: agg(h16) -> GEMM -> h16 (relu)
    k_agg256<<<aggb, 256, 0, stream>>>(h16, dis, rowptr, colA, A16, N);
    k_mgemm<HDIM, 1><<<gemmb, 256, 0, stream>>>(A16, W1t, b1, h16, N);
    // layer 2: agg(h16) -> GEMM -> h16 (no relu)
    k_agg256<<<aggb, 256, 0, stream>>>(h16, dis, rowptr, colA, A16, N);
    k_mgemm<HDIM, 0><<<gemmb, 256, 0, stream>>>(A16, W2t, b2, h16, N);

    // fused mean-pool + MLP head
    k_head<<<B, 256, 0, stream>>>(h16, gstart, uidx, vidx, Wm1, bm1, Wm2, bm2, out);
}